// Round 15
// baseline (114.606 us; speedup 1.0000x reference)
//
#include <hip/hip_runtime.h>
#include <hip/hip_bf16.h>

#define QP 2500
#define KP 1344
#define SCALE 0.088388347648318447f
#define LOG2E 1.4426950408889634f
#define LNEPS 1e-5f

typedef __attribute__((ext_vector_type(8))) short bf16x8;
typedef __attribute__((ext_vector_type(4))) float f32x4;
typedef __attribute__((ext_vector_type(16))) float f32x16;

__device__ inline ushort f2bf(float x) {
  uint u = __float_as_uint(x);
  return (ushort)((u + 0x7fffu + ((u >> 16) & 1u)) >> 16);
}

union Frag8 { uint2 u[2]; bf16x8 f; ushort us[8]; };

__device__ inline bf16x8 ldfrag_swz(const char* rowbase, int colbyte, int C) {
  Frag8 t;
  t.u[0] = *(const uint2*)(rowbase + ((colbyte) ^ C));
  t.u[1] = *(const uint2*)(rowbase + ((colbyte + 8) ^ C));
  return t.f;
}

__device__ inline uint pk2(float a, float b) {
  union { __hip_bfloat162 h; uint u; } cv;
  cv.h = __float22bfloat162_rn(make_float2(a, b));
  return cv.u;
}

// ---------- prep: all six weight matrices -> bf16 transposed [j][k] ----------
__global__ __launch_bounds__(256) void wprep_kernel(
    const float* __restrict__ wq, const float* __restrict__ wk, const float* __restrict__ wv,
    const float* __restrict__ wo, const float* __restrict__ w1, const float* __restrict__ w2,
    ushort* __restrict__ wtq, ushort* __restrict__ wtk, ushort* __restrict__ wtv,
    ushort* __restrict__ woT, ushort* __restrict__ w1T, ushort* __restrict__ w2T)
{
  const int y = blockIdx.y;
  const float* W; ushort* WT; int jsh, K, total;
  switch (y) {
    case 0: W = wq; WT = wtq; jsh = 7; K = 128; total = 16384; break;
    case 1: W = wk; WT = wtk; jsh = 7; K = 128; total = 16384; break;
    case 2: W = wv; WT = wtv; jsh = 7; K = 128; total = 16384; break;
    case 3: W = wo; WT = woT; jsh = 7; K = 128; total = 16384; break;
    case 4: W = w1; WT = w1T; jsh = 8; K = 128; total = 32768; break;
    default: W = w2; WT = w2T; jsh = 7; K = 256; total = 32768; break;
  }
  const int idx = blockIdx.x * 1024 + threadIdx.x * 4;
  if (idx >= total) return;
  const int k = idx >> jsh, j0 = idx & ((1 << jsh) - 1);
  float4 rd = *(const float4*)&W[idx];
  WT[(j0 + 0) * K + k] = f2bf(rd.x);
  WT[(j0 + 1) * K + k] = f2bf(rd.y);
  WT[(j0 + 2) * K + k] = f2bf(rd.z);
  WT[(j0 + 3) * K + k] = f2bf(rd.w);
}

// ---------- MFMA projection: x^T -> LayerNorm -> @W+bias -> bf16 ----------
// z=0: q natural [bn][p][128]; z=1: K swizzled tile image; z=2: V^T swizzled tile image
__global__ __launch_bounds__(256) void proj_kernel(
    const float* __restrict__ qin, const float* __restrict__ kin, const float* __restrict__ vin,
    const float* __restrict__ lnqw, const float* __restrict__ lnqb,
    const float* __restrict__ lnkw, const float* __restrict__ lnkb,
    const float* __restrict__ lnvw, const float* __restrict__ lnvb,
    const ushort* __restrict__ wtq_, const ushort* __restrict__ wtk_, const ushort* __restrict__ wtv_,
    const float* __restrict__ bq_, const float* __restrict__ bk_, const float* __restrict__ bv_,
    ushort* __restrict__ qout, ushort* __restrict__ kout, ushort* __restrict__ vtout)
{
  const int z = blockIdx.z;
  if (z > 0 && blockIdx.x >= 21) return;

  const float *in, *lnw, *lnb, *bias;
  const ushort* WT;
  int P;
  if (z == 0)      { in = qin; lnw = lnqw; lnb = lnqb; WT = wtq_; bias = bq_; P = QP; }
  else if (z == 1) { in = kin; lnw = lnkw; lnb = lnkb; WT = wtk_; bias = bk_; P = KP; }
  else             { in = vin; lnw = lnvw; lnb = lnvb; WT = wtv_; bias = bv_; P = KP; }

  __shared__ __align__(16) ushort xb[64][128];
  __shared__ __align__(16) ushort wt[128][128];
  __shared__ float ps[4][64], pq[4][64];
  __shared__ float mu_s[64], rs_s[64];

  const int bn = blockIdx.y;
  const int p0 = blockIdx.x * 64;
  const int t  = threadIdx.x;
  const int w = t >> 6, lane = t & 63, g = lane >> 4, ln15 = lane & 15;

  #pragma unroll
  for (int i = 0; i < 8; ++i) {
    int idx8 = t + 256 * i;
    int j = idx8 >> 4, ck = (idx8 & 15) * 16;
    *(uint4*)((char*)wt + j * 256 + (ck ^ ((j & 7) << 4))) =
        *(const uint4*)((const char*)WT + j * 256 + ck);
  }

  const float* src = in + ((size_t)bn * 128) * P + p0;
  const int p = t & 63, dq = t >> 6;
  float xv[32];
  float s = 0.f, s2 = 0.f;
  #pragma unroll
  for (int kk = 0; kk < 32; ++kk) {
    int d = dq + 4 * kk;
    float v = (p0 + p < P) ? src[(size_t)d * P + p] : 0.f;
    xv[kk] = v; s += v; s2 += v * v;
  }
  ps[dq][p] = s; pq[dq][p] = s2;
  __syncthreads();
  if (t < 64) {
    float a = ps[0][t] + ps[1][t] + ps[2][t] + ps[3][t];
    float b = pq[0][t] + pq[1][t] + pq[2][t] + pq[3][t];
    float mu = a * (1.f / 128.f);
    float var = b * (1.f / 128.f) - mu * mu;
    mu_s[t] = mu; rs_s[t] = rsqrtf(var + LNEPS);
  }
  __syncthreads();
  {
    const float mu = mu_s[p], rs = rs_s[p];
    const int CW = (p & 7) << 4;
    #pragma unroll
    for (int kk = 0; kk < 32; ++kk) {
      int d = dq + 4 * kk;
      float v = (xv[kk] - mu) * rs * lnw[d] + lnb[d];
      *(ushort*)((char*)xb + p * 256 + ((2 * d) ^ CW)) = f2bf(v);
    }
  }
  __syncthreads();

  const int prow = w * 16 + ln15;
  const char* xrow = (const char*)xb + prow * 256;
  const int CX = (prow & 7) << 4;
  const int CB = (ln15 & 7) << 4;
  const f32x4 zf = {0.f, 0.f, 0.f, 0.f};
  f32x4 acc[8];
  #pragma unroll
  for (int jc = 0; jc < 8; ++jc) acc[jc] = zf;

  #pragma unroll
  for (int ks = 0; ks < 4; ++ks) {
    bf16x8 a = ldfrag_swz(xrow, ks * 64 + g * 16, CX);
    #pragma unroll
    for (int jc = 0; jc < 8; ++jc) {
      bf16x8 b = ldfrag_swz((const char*)wt + (jc * 16 + ln15) * 256, ks * 64 + g * 16, CB);
      acc[jc] = __builtin_amdgcn_mfma_f32_16x16x32_bf16(a, b, acc[jc], 0, 0, 0);
    }
  }

  if (z == 0) {
    const float os = SCALE * LOG2E;
    #pragma unroll
    for (int jc = 0; jc < 8; ++jc) {
      const float bj = bias[jc * 16 + ln15];
      #pragma unroll
      for (int r = 0; r < 4; ++r) {
        int pr = p0 + w * 16 + 4 * g + r;
        if (pr < P)
          qout[((size_t)bn * P + pr) * 128 + jc * 16 + ln15] = f2bf((acc[jc][r] + bj) * os);
      }
    }
  } else if (z == 1) {
    // K tile image: us idx = tile*2048 + r*32 + ((gk + (r>>1))&3)*8 + pos
    #pragma unroll
    for (int jc = 0; jc < 8; ++jc) {
      const int j = jc * 16 + ln15;
      const int h = j >> 5, dh = j & 31, gk = dh >> 3, pos = dh & 7;
      const float bj = bias[j];
      #pragma unroll
      for (int r4 = 0; r4 < 4; ++r4) {
        int pp = p0 + w * 16 + 4 * g + r4;
        int kt = pp >> 6, r = pp & 63;
        int ch = (gk + (r >> 1)) & 3;
        kout[(size_t)((bn * 4 + h) * 21 + kt) * 2048 + r * 32 + ch * 8 + pos] =
            f2bf(acc[jc][r4] + bj);
      }
    }
  } else {
    // V^T tile image: us idx = tile*2048 + rdh*64 + ((kk>>3)^(rdh&7))*8 + (kk&7)
    #pragma unroll
    for (int jc = 0; jc < 8; ++jc) {
      const int j = jc * 16 + ln15;
      const int h = j >> 5, rdh = j & 31;
      const float bj = bias[j];
      #pragma unroll
      for (int r4 = 0; r4 < 4; ++r4) {
        int pp = p0 + w * 16 + 4 * g + r4;
        int kt = pp >> 6, kk = pp & 63;
        int ch = (kk >> 3) ^ (rdh & 7);
        vtout[(size_t)((bn * 4 + h) * 21 + kt) * 2048 + rdh * 64 + ch * 8 + (kk & 7)] =
            f2bf(acc[jc][r4] + bj);
      }
    }
  }
}

// ---------- zero-LDS 32x32-MFMA flash attention: P in registers via permlane32_swap ----------
// block: 4 independent waves x 32 q = 128 q rows; K/V direct from swizzled global images.
__global__ __launch_bounds__(256, 4) void attn_kernel(
    const ushort* __restrict__ qh, const ushort* __restrict__ kimg,
    const ushort* __restrict__ vimg, float* __restrict__ aw,
    float* __restrict__ ml)
{
  // XCD-aware bijective swizzle: 960 = 8 * 120
  const int lin = blockIdx.x + 20 * (blockIdx.y + 4 * blockIdx.z);
  const int sid = (lin & 7) * 120 + (lin >> 3);
  const int bx = sid % 20;
  const int hh = (sid / 20) & 3;
  const int bn = sid / 80;

  const int q0 = bx * 128;
  const int t = threadIdx.x;
  const int w = t >> 6;
  const int lane = t & 63;
  const int lk = lane & 31;
  const int hi = lane >> 5;

  // Q fragments (B-operand of 32x32x16): lane holds Q[q=q0+w*32+lk][dh = slice*16 + hi*8 + j]
  bf16x8 qf0, qf1;
  {
    Frag8 z_; z_.u[0] = make_uint2(0, 0); z_.u[1] = make_uint2(0, 0);
    int qrow = q0 + w * 32 + lk;
    if (qrow < QP) {
      const ushort* qp = &qh[((size_t)bn * QP + qrow) * 128 + hh * 32 + hi * 8];
      qf0 = *(const bf16x8*)(qp);
      qf1 = *(const bf16x8*)(qp + 16);
    } else { qf0 = z_.f; qf1 = z_.f; }
  }

  const size_t slab = (size_t)((bn * 4 + hh) * 21) * 2048;
  const ushort* kb = kimg + slab;   // + kt*2048; frag: key*32 + ((cn + (key>>1))&3)*8
  const ushort* vb = vimg + slab;   // + kt*2048; frag: lk*64 + chunk*8

  f32x16 O;
  #pragma unroll
  for (int i = 0; i < 16; ++i) O[i] = 0.f;
  float lpart = 0.f;

  for (int kt = 0; kt < 21; ++kt) {
    const ushort* kp = kb + (size_t)kt * 2048;
    const ushort* vp = vb + (size_t)kt * 2048;

    #pragma unroll
    for (int kc2 = 0; kc2 < 2; ++kc2) {
      // ---- QK^T: S[k = kc2*32 + crow(reg,hi)][q = lk]  (R12-verified K image math) ----
      const int key = kc2 * 32 + lk;
      f32x16 S;
      #pragma unroll
      for (int i = 0; i < 16; ++i) S[i] = 0.f;
      {
        bf16x8 kfa = *(const bf16x8*)(kp + key * 32 + ((hi     + (key >> 1)) & 3) * 8);
        bf16x8 kfb = *(const bf16x8*)(kp + key * 32 + ((2 + hi + (key >> 1)) & 3) * 8);
        __builtin_amdgcn_s_setprio(1);
        S = __builtin_amdgcn_mfma_f32_32x32x16_bf16(kfa, qf0, S, 0, 0, 0);
        S = __builtin_amdgcn_mfma_f32_32x32x16_bf16(kfb, qf1, S, 0, 0, 0);
        __builtin_amdgcn_s_setprio(0);
      }

      // ---- P = exp2(S) (|S| << 1, no max), l partial, pack to bf16 words ----
      float e0 = exp2f(S[0]),  e1 = exp2f(S[1]),  e2 = exp2f(S[2]),  e3 = exp2f(S[3]);
      float e4 = exp2f(S[4]),  e5 = exp2f(S[5]),  e6 = exp2f(S[6]),  e7 = exp2f(S[7]);
      float e8 = exp2f(S[8]),  e9 = exp2f(S[9]),  e10 = exp2f(S[10]), e11 = exp2f(S[11]);
      float e12 = exp2f(S[12]), e13 = exp2f(S[13]), e14 = exp2f(S[14]), e15 = exp2f(S[15]);
      lpart += (((e0 + e1) + (e2 + e3)) + ((e4 + e5) + (e6 + e7)))
             + (((e8 + e9) + (e10 + e11)) + ((e12 + e13) + (e14 + e15)));
      uint w0 = pk2(e0, e1),  w1 = pk2(e2, e3),  w2 = pk2(e4, e5),  w3 = pk2(e6, e7);
      uint w4 = pk2(e8, e9),  w5 = pk2(e10, e11), w6 = pk2(e12, e13), w7 = pk2(e14, e15);

      // ---- redistribute across lane halves (verified in R10/R12) ----
      asm volatile("v_permlane32_swap_b32 %0, %1" : "+v"(w2), "+v"(w0));
      asm volatile("v_permlane32_swap_b32 %0, %1" : "+v"(w3), "+v"(w1));
      asm volatile("v_permlane32_swap_b32 %0, %1" : "+v"(w6), "+v"(w4));
      asm volatile("v_permlane32_swap_b32 %0, %1" : "+v"(w7), "+v"(w5));

      // ---- PV: O[q][dh] += P @ V  (R12-verified V image math) ----
      Frag8 pa0, pa1;
      pa0.u[0] = make_uint2(w0, w1); pa0.u[1] = make_uint2(w2, w3);
      pa1.u[0] = make_uint2(w4, w5); pa1.u[1] = make_uint2(w6, w7);
      bf16x8 vf0 = *(const bf16x8*)(vp + lk * 64 + (((kc2 * 4 + 0 + hi) ^ (lk & 7)) * 8));
      bf16x8 vf1 = *(const bf16x8*)(vp + lk * 64 + (((kc2 * 4 + 2 + hi) ^ (lk & 7)) * 8));
      __builtin_amdgcn_s_setprio(1);
      O = __builtin_amdgcn_mfma_f32_32x32x16_bf16(pa0.f, vf0, O, 0, 0, 0);
      O = __builtin_amdgcn_mfma_f32_32x32x16_bf16(pa1.f, vf1, O, 0, 0, 0);
      __builtin_amdgcn_s_setprio(0);
    }
  }

  // ---- l: combine lane halves; store l + unnormalized O ----
  float lsum = lpart + __shfl_xor(lpart, 32);
  {
    int qrow = q0 + w * 32 + lk;
    if (hi == 0 && qrow < QP)
      ml[((size_t)bn * QP + qrow) * 4 + hh] = lsum;
  }
  #pragma unroll
  for (int reg = 0; reg < 16; ++reg) {
    int crow = (reg & 3) + 8 * (reg >> 2) + 4 * hi;
    int qrow = q0 + w * 32 + crow;
    if (qrow < QP)
      aw[((size_t)bn * QP + qrow) * 128 + hh * 32 + lk] = O[reg];
  }
}

// ---------- MFMA epilogue: combine -> a@wo+bo+skip^T -> LN -> MLP(gelu) -> +res -> LN -> store^T ----------
__global__ __launch_bounds__(256) void epilogue_kernel(
    const float* __restrict__ aw, const float* __restrict__ ml,
    const float* __restrict__ skip,
    const ushort* __restrict__ woT, const float* __restrict__ bo,
    const float* __restrict__ lnpw, const float* __restrict__ lnpb,
    const ushort* __restrict__ w1T, const float* __restrict__ b1,
    const ushort* __restrict__ w2T, const float* __restrict__ b2,
    const float* __restrict__ lnqw, const float* __restrict__ lnqb,
    float* __restrict__ out)
{
  __shared__ __align__(16) ushort xa[16][128];
  __shared__ __align__(16) ushort znb[16][128];
  __shared__ __align__(16) ushort hb[16][256];
  __shared__ float skp[128][17];
  __shared__ float2 red[4][16];
  __shared__ float mu_s[16], rs_s[16];
  __shared__ float cc[16][4];

  const int b = blockIdx.y;
  const int q0 = blockIdx.x * 16;
  const int t = threadIdx.x;
  const int w = t >> 6, lane = t & 63, g = lane >> 4, ln15 = lane & 15;
  const f32x4 zf = {0.f, 0.f, 0.f, 0.f};

  if (t < 64) {
    int r = t >> 2, h = t & 3;
    int qrow = q0 + r;
    float inv = 0.f;
    if (qrow < QP) {
      float sum = 0.f;
      #pragma unroll
      for (int n = 0; n < 6; ++n)
        sum += ml[((size_t)(b * 6 + n) * QP + qrow) * 4 + h];
      inv = 1.f / sum;
    }
    cc[r][h] = inv;
  }
  #pragma unroll
  for (int i = 0; i < 8; ++i) {
    int idx = t + 256 * i;
    int j = idx >> 4, r = idx & 15;
    int qrow = q0 + r;
    skp[j][r] = (qrow < QP) ? skip[((size_t)b * 128 + j) * QP + qrow] : 0.f;
  }
  __syncthreads();

  #pragma unroll
  for (int i = 0; i < 4; ++i) {
    int idx = t + 256 * i;
    int r = idx >> 6, jp = idx & 63;
    int qrow = q0 + r;
    float v0 = 0.f, v1 = 0.f;
    if (qrow < QP) {
      #pragma unroll
      for (int n = 0; n < 6; ++n) {
        float2 p = *(const float2*)&aw[((size_t)(b * 6 + n) * QP + qrow) * 128 + 2 * jp];
        v0 += p.x; v1 += p.y;
      }
      float iv = cc[r][jp >> 4];
      v0 *= iv; v1 *= iv;
    }
    *(uint*)((char*)xa + r * 256 + ((4 * jp) ^ ((r & 7) << 4))) = pk2(v0, v1);
  }
  __syncthreads();

  f32x4 acc1[2] = {zf, zf};
  #pragma unroll
  for (int ks = 0; ks < 4; ++ks) {
    bf16x8 a = ldfrag_swz((const char*)xa + ln15 * 256, ks * 64 + g * 16, (ln15 & 7) << 4);
    #pragma unroll
    for (int jc = 0; jc < 2; ++jc) {
      int j = (2 * w + jc) * 16 + ln15;
      bf16x8 bfr = *(const bf16x8*)&woT[j * 128 + ks * 32 + g * 8];
      acc1[jc] = __builtin_amdgcn_mfma_f32_16x16x32_bf16(a, bfr, acc1[jc], 0, 0, 0);
    }
  }
  float z[2][4];
  #pragma unroll
  for (int jc = 0; jc < 2; ++jc) {
    int j = (2 * w + jc) * 16 + ln15;
    float bj = bo[j];
    #pragma unroll
    for (int i = 0; i < 4; ++i)
      z[jc][i] = acc1[jc][i] + bj + skp[j][4 * g + i];
  }
  {
    float s_[4], q_[4];
    #pragma unroll
    for (int i = 0; i < 4; ++i) {
      s_[i] = z[0][i] + z[1][i];
      q_[i] = z[0][i] * z[0][i] + z[1][i] * z[1][i];
    }
    #pragma unroll
    for (int m = 1; m <= 8; m <<= 1) {
      #pragma unroll
      for (int i = 0; i < 4; ++i) {
        s_[i] += __shfl_xor(s_[i], m);
        q_[i] += __shfl_xor(q_[i], m);
      }
    }
    if (ln15 == 0) {
      #pragma unroll
      for (int i = 0; i < 4; ++i) red[w][4 * g + i] = make_float2(s_[i], q_[i]);
    }
  }
  __syncthreads();
  if (t < 16) {
    float S = red[0][t].x + red[1][t].x + red[2][t].x + red[3][t].x;
    float Q = red[0][t].y + red[1][t].y + red[2][t].y + red[3][t].y;
    float mu = S * (1.f / 128.f);
    float var = Q * (1.f / 128.f) - mu * mu;
    mu_s[t] = mu; rs_s[t] = rsqrtf(var + LNEPS);
  }
  __syncthreads();
  float zn[2][4];
  #pragma unroll
  for (int jc = 0; jc < 2; ++jc) {
    int j = (2 * w + jc) * 16 + ln15;
    float lw = lnpw[j], lb = lnpb[j];
    #pragma unroll
    for (int i = 0; i < 4; ++i) {
      int r = 4 * g + i;
      float v = (z[jc][i] - mu_s[r]) * rs_s[r] * lw + lb;
      zn[jc][i] = v;
      *(ushort*)((char*)znb + r * 256 + ((2 * j) ^ ((r & 7) << 4))) = f2bf(v);
    }
  }
  __syncthreads();

  f32x4 acc2[4] = {zf, zf, zf, zf};
  #pragma unroll
  for (int ks = 0; ks < 4; ++ks) {
    bf16x8 a = ldfrag_swz((const char*)znb + ln15 * 256, ks * 64 + g * 16, (ln15 & 7) << 4);
    #pragma unroll
    for (int jc2 = 0; jc2 < 4; ++jc2) {
      int j2 = (4 * w + jc2) * 16 + ln15;
      bf16x8 bfr = *(const bf16x8*)&w1T[j2 * 128 + ks * 32 + g * 8];
      acc2[jc2] = __builtin_amdgcn_mfma_f32_16x16x32_bf16(a, bfr, acc2[jc2], 0, 0, 0);
    }
  }
  #pragma unroll
  for (int jc2 = 0; jc2 < 4; ++jc2) {
    int j2 = (4 * w + jc2) * 16 + ln15;
    float bj = b1[j2];
    #pragma unroll
    for (int i = 0; i < 4; ++i) {
      float x = acc2[jc2][i] + bj;
      float ge = 0.5f * x * (1.f + erff(x * 0.70710678118654752f));
      int r = 4 * g + i;
      *(ushort*)((char*)hb + r * 512 + ((2 * j2) ^ ((r & 7) << 4))) = f2bf(ge);
    }
  }
  __syncthreads();

  f32x4 acc3[2] = {zf, zf};
  #pragma unroll
  for (int ks = 0; ks < 8; ++ks) {
    bf16x8 a = ldfrag_swz((const char*)hb + ln15 * 512, ks * 64 + g * 16, (ln15 & 7) << 4);
    #pragma unroll
    for (int jc = 0; jc < 2; ++jc) {
      int j = (2 * w + jc) * 16 + ln15;
      bf16x8 bfr = *(const bf16x8*)&w2T[j * 256 + ks * 32 + g * 8];
      acc3[jc] = __builtin_amdgcn_mfma_f32_16x16x32_bf16(a, bfr, acc3[jc], 0, 0, 0);
    }
  }
  float z2[2][4];
  #pragma unroll
  for (int jc = 0; jc < 2; ++jc) {
    int j = (2 * w + jc) * 16 + ln15;
    float bj = b2[j];
    #pragma unroll
    for (int i = 0; i < 4; ++i)
      z2[jc][i] = acc3[jc][i] + bj + zn[jc][i];
  }
  {
    float s_[4], q_[4];
    #pragma unroll
    for (int i = 0; i < 4; ++i) {
      s_[i] = z2[0][i] + z2[1][i];
      q_[i] = z2[0][i] * z2[0][i] + z2[1][i] * z2[1][i];
    }
    #pragma unroll
    for (int m = 1; m <= 8; m <<= 1) {
      #pragma unroll
      for (int i = 0; i < 4; ++i) {
        s_[i] += __shfl_xor(s_[i], m);
        q_[i] += __shfl_xor(q_[i], m);
      }
    }
    if (ln15 == 0) {
      #pragma unroll
      for (int i = 0; i < 4; ++i) red[w][4 * g + i] = make_float2(s_[i], q_[i]);
    }
  }
  __syncthreads();
  if (t < 16) {
    float S = red[0][t].x + red[1][t].x + red[2][t].x + red[3][t].x;
    float Q = red[0][t].y + red[1][t].y + red[2][t].y + red[3][t].y;
    float mu = S * (1.f / 128.f);
    float var = Q * (1.f / 128.f) - mu * mu;
    mu_s[t] = mu; rs_s[t] = rsqrtf(var + LNEPS);
  }
  __syncthreads();
  #pragma unroll
  for (int jc = 0; jc < 2; ++jc) {
    int j = (2 * w + jc) * 16 + ln15;
    float lw = lnqw[j], lb = lnqb[j];
    #pragma unroll
    for (int i = 0; i < 4; ++i) {
      int r = 4 * g + i;
      skp[j][r] = (z2[jc][i] - mu_s[r]) * rs_s[r] * lw + lb;
    }
  }
  __syncthreads();
  #pragma unroll
  for (int i = 0; i < 8; ++i) {
    int idx = t + 256 * i;
    int j = idx >> 4, r = idx & 15;
    int qrow = q0 + r;
    if (qrow < QP)
      out[((size_t)b * 128 + j) * QP + qrow] = skp[j][r];
  }
}

extern "C" void kernel_launch(void* const* d_in, const int* in_sizes, int n_in,
                              void* d_out, int out_size, void* d_ws, size_t ws_size,
                              hipStream_t stream) {
  const float* q       = (const float*)d_in[0];
  const float* k       = (const float*)d_in[1];
  const float* v       = (const float*)d_in[2];
  const float* skip    = (const float*)d_in[3];
  const float* ln_q_w  = (const float*)d_in[4];
  const float* ln_q_b  = (const float*)d_in[5];
  const float* wq      = (const float*)d_in[6];
  const float* bq      = (const float*)d_in[7];
  const float* ln_k_w  = (const float*)d_in[8];
  const float* ln_k_b  = (const float*)d_in[9];
  const float* wk      = (const float*)d_in[10];
  const float* bk      = (const float*)d_in[11];
  const float* ln_v_w  = (const float*)d_in[12];
  const float* ln_v_b  = (const float*)d_in[13];
  const float* wv      = (const float*)d_in[14];
  const float* bv      = (const float*)d_in[15];
  const float* wo      = (const float*)d_in[16];
  const float* bo      = (const float*)d_in[17];
  const float* ln_pre_w  = (const float*)d_in[18];
  const float* ln_pre_b  = (const float*)d_in[19];
  const float* w1      = (const float*)d_in[20];
  const float* b1      = (const float*)d_in[21];
  const float* w2      = (const float*)d_in[22];
  const float* b2      = (const float*)d_in[23];
  const float* ln_post_w = (const float*)d_in[24];
  const float* ln_post_b = (const float*)d_in[25];

  float* out = (float*)d_out;
  ushort* qhp  = (ushort*)d_ws;            // 3,840,000 bf16
  ushort* kimg = qhp + 3840000;            // 2,064,384 bf16
  ushort* vimg = kimg + 2064384;           // 2,064,384 bf16
  ushort* wtq  = vimg + 2064384;           // 16,384 bf16
  ushort* wtk  = wtq + 16384;
  ushort* wtv  = wtk + 16384;
  ushort* woT  = wtv + 16384;              // 16,384 bf16
  ushort* w1T  = woT + 16384;              // 32,768 bf16
  ushort* w2T  = w1T + 32768;              // 32,768 bf16
  float*  aw   = (float*)(w2T + 32768);    // [bn][q][128] = 3,840,000 f32
  float*  ml   = aw + 3840000;             // [bn][q][h] = 120,000 f32

  wprep_kernel<<<dim3(32, 6), 256, 0, stream>>>(wq, wk, wv, wo, w1, w2,
      wtq, wtk, wtv, woT, w1T, w2T);
  proj_kernel<<<dim3(40, 12, 3), 256, 0, stream>>>(q, k, v,
      ln_q_w, ln_q_b, ln_k_w, ln_k_b, ln_v_w, ln_v_b,
      wtq, wtk, wtv, bq, bk, bv, qhp, kimg, vimg);
  attn_kernel<<<dim3(20, 4, 12), 256, 0, stream>>>(qhp, kimg, vimg, aw, ml);
  epilogue_kernel<<<dim3(157, 2), 256, 0, stream>>>(aw, ml, skip, woT, bo,
      ln_pre_w, ln_pre_b, w1T, b1, w2T, b2, ln_post_w, ln_post_b, out);
}

// Round 16
// 107.543 us; speedup vs baseline: 1.0657x; 1.0657x over previous
//
#include <hip/hip_runtime.h>
#include <hip/hip_bf16.h>

#define QP 2500
#define KP 1344
#define SCALE 0.088388347648318447f
#define LOG2E 1.4426950408889634f
#define LNEPS 1e-5f

typedef __attribute__((ext_vector_type(8))) short bf16x8;
typedef __attribute__((ext_vector_type(4))) float f32x4;

__device__ inline ushort f2bf(float x) {
  uint u = __float_as_uint(x);
  return (ushort)((u + 0x7fffu + ((u >> 16) & 1u)) >> 16);
}

union Frag8 { uint2 u[2]; bf16x8 f; ushort us[8]; };

__device__ inline bf16x8 ldfrag_swz(const char* rowbase, int colbyte, int C) {
  Frag8 t;
  t.u[0] = *(const uint2*)(rowbase + ((colbyte) ^ C));
  t.u[1] = *(const uint2*)(rowbase + ((colbyte + 8) ^ C));
  return t.f;
}

__device__ inline uint pk2(float a, float b) {
  union { __hip_bfloat162 h; uint u; } cv;
  cv.h = __float22bfloat162_rn(make_float2(a, b));
  return cv.u;
}

// async global -> LDS DMA, 16B per lane; dest = lds base (wave-uniform) + lane*16
__device__ inline void gld16(const ushort* g, ushort* l) {
  __builtin_amdgcn_global_load_lds(
      (const __attribute__((address_space(1))) void*)g,
      (__attribute__((address_space(3))) void*)l, 16, 0, 0);
}

// ---------- prep: all six weight matrices -> bf16 transposed [j][k] ----------
__global__ __launch_bounds__(256) void wprep_kernel(
    const float* __restrict__ wq, const float* __restrict__ wk, const float* __restrict__ wv,
    const float* __restrict__ wo, const float* __restrict__ w1, const float* __restrict__ w2,
    ushort* __restrict__ wtq, ushort* __restrict__ wtk, ushort* __restrict__ wtv,
    ushort* __restrict__ woT, ushort* __restrict__ w1T, ushort* __restrict__ w2T)
{
  const int y = blockIdx.y;
  const float* W; ushort* WT; int jsh, K, total;
  switch (y) {
    case 0: W = wq; WT = wtq; jsh = 7; K = 128; total = 16384; break;
    case 1: W = wk; WT = wtk; jsh = 7; K = 128; total = 16384; break;
    case 2: W = wv; WT = wtv; jsh = 7; K = 128; total = 16384; break;
    case 3: W = wo; WT = woT; jsh = 7; K = 128; total = 16384; break;
    case 4: W = w1; WT = w1T; jsh = 8; K = 128; total = 32768; break;
    default: W = w2; WT = w2T; jsh = 7; K = 256; total = 32768; break;
  }
  const int idx = blockIdx.x * 1024 + threadIdx.x * 4;
  if (idx >= total) return;
  const int k = idx >> jsh, j0 = idx & ((1 << jsh) - 1);
  float4 rd = *(const float4*)&W[idx];
  WT[(j0 + 0) * K + k] = f2bf(rd.x);
  WT[(j0 + 1) * K + k] = f2bf(rd.y);
  WT[(j0 + 2) * K + k] = f2bf(rd.z);
  WT[(j0 + 3) * K + k] = f2bf(rd.w);
}

// ---------- MFMA projection: x^T -> LayerNorm -> @W+bias -> bf16 ----------
// z=0: q natural [bn][p][128]; z=1: K swizzled tile image; z=2: V^T swizzled tile image
__global__ __launch_bounds__(256) void proj_kernel(
    const float* __restrict__ qin, const float* __restrict__ kin, const float* __restrict__ vin,
    const float* __restrict__ lnqw, const float* __restrict__ lnqb,
    const float* __restrict__ lnkw, const float* __restrict__ lnkb,
    const float* __restrict__ lnvw, const float* __restrict__ lnvb,
    const ushort* __restrict__ wtq_, const ushort* __restrict__ wtk_, const ushort* __restrict__ wtv_,
    const float* __restrict__ bq_, const float* __restrict__ bk_, const float* __restrict__ bv_,
    ushort* __restrict__ qout, ushort* __restrict__ kout, ushort* __restrict__ vtout)
{
  const int z = blockIdx.z;
  if (z > 0 && blockIdx.x >= 21) return;

  const float *in, *lnw, *lnb, *bias;
  const ushort* WT;
  int P;
  if (z == 0)      { in = qin; lnw = lnqw; lnb = lnqb; WT = wtq_; bias = bq_; P = QP; }
  else if (z == 1) { in = kin; lnw = lnkw; lnb = lnkb; WT = wtk_; bias = bk_; P = KP; }
  else             { in = vin; lnw = lnvw; lnb = lnvb; WT = wtv_; bias = bv_; P = KP; }

  __shared__ __align__(16) ushort xb[64][128];
  __shared__ __align__(16) ushort wt[128][128];
  __shared__ float ps[4][64], pq[4][64];
  __shared__ float mu_s[64], rs_s[64];

  const int bn = blockIdx.y;
  const int p0 = blockIdx.x * 64;
  const int t  = threadIdx.x;
  const int w = t >> 6, lane = t & 63, g = lane >> 4, ln15 = lane & 15;

  #pragma unroll
  for (int i = 0; i < 8; ++i) {
    int idx8 = t + 256 * i;
    int j = idx8 >> 4, ck = (idx8 & 15) * 16;
    *(uint4*)((char*)wt + j * 256 + (ck ^ ((j & 7) << 4))) =
        *(const uint4*)((const char*)WT + j * 256 + ck);
  }

  const float* src = in + ((size_t)bn * 128) * P + p0;
  const int p = t & 63, dq = t >> 6;
  float xv[32];
  float s = 0.f, s2 = 0.f;
  #pragma unroll
  for (int kk = 0; kk < 32; ++kk) {
    int d = dq + 4 * kk;
    float v = (p0 + p < P) ? src[(size_t)d * P + p] : 0.f;
    xv[kk] = v; s += v; s2 += v * v;
  }
  ps[dq][p] = s; pq[dq][p] = s2;
  __syncthreads();
  if (t < 64) {
    float a = ps[0][t] + ps[1][t] + ps[2][t] + ps[3][t];
    float b = pq[0][t] + pq[1][t] + pq[2][t] + pq[3][t];
    float mu = a * (1.f / 128.f);
    float var = b * (1.f / 128.f) - mu * mu;
    mu_s[t] = mu; rs_s[t] = rsqrtf(var + LNEPS);
  }
  __syncthreads();
  {
    const float mu = mu_s[p], rs = rs_s[p];
    const int CW = (p & 7) << 4;
    #pragma unroll
    for (int kk = 0; kk < 32; ++kk) {
      int d = dq + 4 * kk;
      float v = (xv[kk] - mu) * rs * lnw[d] + lnb[d];
      *(ushort*)((char*)xb + p * 256 + ((2 * d) ^ CW)) = f2bf(v);
    }
  }
  __syncthreads();

  const int prow = w * 16 + ln15;
  const char* xrow = (const char*)xb + prow * 256;
  const int CX = (prow & 7) << 4;
  const int CB = (ln15 & 7) << 4;
  const f32x4 zf = {0.f, 0.f, 0.f, 0.f};
  f32x4 acc[8];
  #pragma unroll
  for (int jc = 0; jc < 8; ++jc) acc[jc] = zf;

  #pragma unroll
  for (int ks = 0; ks < 4; ++ks) {
    bf16x8 a = ldfrag_swz(xrow, ks * 64 + g * 16, CX);
    #pragma unroll
    for (int jc = 0; jc < 8; ++jc) {
      bf16x8 b = ldfrag_swz((const char*)wt + (jc * 16 + ln15) * 256, ks * 64 + g * 16, CB);
      acc[jc] = __builtin_amdgcn_mfma_f32_16x16x32_bf16(a, b, acc[jc], 0, 0, 0);
    }
  }

  if (z == 0) {
    const float os = SCALE * LOG2E;
    #pragma unroll
    for (int jc = 0; jc < 8; ++jc) {
      const float bj = bias[jc * 16 + ln15];
      #pragma unroll
      for (int r = 0; r < 4; ++r) {
        int pr = p0 + w * 16 + 4 * g + r;
        if (pr < P)
          qout[((size_t)bn * P + pr) * 128 + jc * 16 + ln15] = f2bf((acc[jc][r] + bj) * os);
      }
    }
  } else if (z == 1) {
    // K tile image: us idx = tile*2048 + r*32 + ((gk + (r>>1))&3)*8 + pos
    #pragma unroll
    for (int jc = 0; jc < 8; ++jc) {
      const int j = jc * 16 + ln15;
      const int h = j >> 5, dh = j & 31, gk = dh >> 3, pos = dh & 7;
      const float bj = bias[j];
      #pragma unroll
      for (int r4 = 0; r4 < 4; ++r4) {
        int pp = p0 + w * 16 + 4 * g + r4;
        int kt = pp >> 6, r = pp & 63;
        int ch = (gk + (r >> 1)) & 3;
        kout[(size_t)((bn * 4 + h) * 21 + kt) * 2048 + r * 32 + ch * 8 + pos] =
            f2bf(acc[jc][r4] + bj);
      }
    }
  } else {
    // V^T tile image: us idx = tile*2048 + rdh*64 + ((kk>>3)^(rdh&7))*8 + (kk&7)
    #pragma unroll
    for (int jc = 0; jc < 8; ++jc) {
      const int j = jc * 16 + ln15;
      const int h = j >> 5, rdh = j & 31;
      const float bj = bias[j];
      #pragma unroll
      for (int r4 = 0; r4 < 4; ++r4) {
        int pp = p0 + w * 16 + 4 * g + r4;
        int kt = pp >> 6, kk = pp & 63;
        int ch = (kk >> 3) ^ (rdh & 7);
        vtout[(size_t)((bn * 4 + h) * 21 + kt) * 2048 + rdh * 64 + ch * 8 + (kk & 7)] =
            f2bf(acc[jc][r4] + bj);
      }
    }
  }
}

// ---------- MFMA flash attention (R13 structure): K via LDS-DMA, V direct global ----------
// block: 4 waves x 16 q = 64 q rows; l via in-lane VALU reduction (no ones-MFMA).
__global__ __launch_bounds__(256, 4) void attn_kernel(
    const ushort* __restrict__ qh, const ushort* __restrict__ kimg,
    const ushort* __restrict__ vimg, float* __restrict__ aw,
    float* __restrict__ ml)
{
  __shared__ __align__(16) ushort Kb[2][2048];
  __shared__ __align__(16) ushort Ps[4][16][64];

  // XCD-aware bijective swizzle: 1920 = 8 * 240
  const int lin = blockIdx.x + 40 * (blockIdx.y + 4 * blockIdx.z);
  const int sid = (lin & 7) * 240 + (lin >> 3);
  const int bx = sid % 40;
  const int hh = (sid / 40) & 3;
  const int bn = sid / 160;

  const int q0 = bx * 64;
  const int t = threadIdx.x;
  const int w = t >> 6, lane = t & 63;
  const int g = lane >> 4, ln15 = lane & 15;
  const int C = ((ln15 & 7) << 4) | (((ln15 >> 3) & 1) << 3);
  const int kch = (g + (ln15 >> 1)) & 3;
  const int vch0 = (0 + g) ^ (ln15 & 7);
  const int vch1 = (4 + g) ^ (ln15 & 7);

  bf16x8 qf;
  {
    Frag8 z_; z_.u[0] = make_uint2(0, 0); z_.u[1] = make_uint2(0, 0);
    int qr = q0 + w * 16 + ln15;
    qf = (qr < QP) ? *(const bf16x8*)&qh[((size_t)bn * QP + qr) * 128 + hh * 32 + g * 8] : z_.f;
  }

  const ushort* ksrc = kimg + (size_t)((bn * 4 + hh) * 21) * 2048 + w * 512 + lane * 8;
  const ushort* vbase0 = vimg + (size_t)((bn * 4 + hh) * 21) * 2048 + ln15 * 64;
  const ushort* vbase1 = vbase0 + 16 * 64;

  gld16(ksrc, &Kb[0][w * 512]);
  __syncthreads();

  const f32x4 zf = {0.f, 0.f, 0.f, 0.f};
  f32x4 o0 = zf, o1 = zf;
  float lpart = 0.f;

  for (int kt = 0; kt < 21; ++kt) {
    const int cur = kt & 1;
    if (kt < 20)
      gld16(ksrc + (size_t)(kt + 1) * 2048, &Kb[cur ^ 1][w * 512]);

    const char* Kbase = (const char*)Kb[cur];
    char* Pw = (char*)Ps[w];

    // ---- QK^T: lane holds S[k = kb*16 + 4g + i][q = ln15] ----
    f32x4 s[4];
    #pragma unroll
    for (int kb = 0; kb < 4; ++kb) {
      bf16x8 kf = *(const bf16x8*)(Kbase + (kb * 16 + ln15) * 64 + kch * 16);
      s[kb] = __builtin_amdgcn_mfma_f32_16x16x32_bf16(kf, qf, zf, 0, 0, 0);
    }

    // ---- P = exp2(S) (|S| << 1, no max), l partial in-lane, pack bf16, write LDS ----
    {
      char* pr = Pw + ln15 * 128;
      #pragma unroll
      for (int kb = 0; kb < 4; ++kb) {
        float e0 = exp2f(s[kb][0]);
        float e1 = exp2f(s[kb][1]);
        float e2 = exp2f(s[kb][2]);
        float e3 = exp2f(s[kb][3]);
        lpart += (e0 + e1) + (e2 + e3);
        uint2 u;
        u.x = pk2(e0, e1);
        u.y = pk2(e2, e3);
        *(uint2*)(pr + ((kb * 32 + g * 8) ^ C)) = u;
      }
    }

    // ---- PV: P from wave-private LDS, V straight from global ----
    {
      const char* pr = Pw + ln15 * 128;
      const ushort* vt0 = vbase0 + (size_t)kt * 2048;
      const ushort* vt1 = vbase1 + (size_t)kt * 2048;
      #pragma unroll
      for (int kc = 0; kc < 2; ++kc) {
        bf16x8 pa = ldfrag_swz(pr, kc * 64 + g * 16, C);
        const int vch = kc ? vch1 : vch0;
        bf16x8 vf0 = *(const bf16x8*)(vt0 + vch * 8);
        bf16x8 vf1 = *(const bf16x8*)(vt1 + vch * 8);
        o0 = __builtin_amdgcn_mfma_f32_16x16x32_bf16(pa, vf0, o0, 0, 0, 0);
        o1 = __builtin_amdgcn_mfma_f32_16x16x32_bf16(pa, vf1, o1, 0, 0, 0);
      }
    }
    __syncthreads();
  }

  // ---- l: in-lane partial summed across the 4 g-groups (lanes sharing ln15) ----
  float lsum = lpart;
  lsum += __shfl_xor(lsum, 16);
  lsum += __shfl_xor(lsum, 32);
  {
    int qr = q0 + w * 16 + ln15;
    if (g == 0 && qr < QP)
      ml[((size_t)bn * QP + qr) * 4 + hh] = lsum;
  }
  #pragma unroll
  for (int i = 0; i < 4; ++i) {
    int qr = q0 + w * 16 + 4 * g + i;
    if (qr < QP) {
      size_t base = ((size_t)bn * QP + qr) * 128 + hh * 32;
      aw[base + ln15] = o0[i];
      aw[base + 16 + ln15] = o1[i];
    }
  }
}

// ---------- MFMA epilogue: combine -> a@wo+bo+skip^T -> LN -> MLP(gelu) -> +res -> LN -> store^T ----------
__global__ __launch_bounds__(256) void epilogue_kernel(
    const float* __restrict__ aw, const float* __restrict__ ml,
    const float* __restrict__ skip,
    const ushort* __restrict__ woT, const float* __restrict__ bo,
    const float* __restrict__ lnpw, const float* __restrict__ lnpb,
    const ushort* __restrict__ w1T, const float* __restrict__ b1,
    const ushort* __restrict__ w2T, const float* __restrict__ b2,
    const float* __restrict__ lnqw, const float* __restrict__ lnqb,
    float* __restrict__ out)
{
  __shared__ __align__(16) ushort xa[16][128];
  __shared__ __align__(16) ushort znb[16][128];
  __shared__ __align__(16) ushort hb[16][256];
  __shared__ float skp[128][17];
  __shared__ float2 red[4][16];
  __shared__ float mu_s[16], rs_s[16];
  __shared__ float cc[16][4];

  const int b = blockIdx.y;
  const int q0 = blockIdx.x * 16;
  const int t = threadIdx.x;
  const int w = t >> 6, lane = t & 63, g = lane >> 4, ln15 = lane & 15;
  const f32x4 zf = {0.f, 0.f, 0.f, 0.f};

  if (t < 64) {
    int r = t >> 2, h = t & 3;
    int qrow = q0 + r;
    float inv = 0.f;
    if (qrow < QP) {
      float sum = 0.f;
      #pragma unroll
      for (int n = 0; n < 6; ++n)
        sum += ml[((size_t)(b * 6 + n) * QP + qrow) * 4 + h];
      inv = 1.f / sum;
    }
    cc[r][h] = inv;
  }
  #pragma unroll
  for (int i = 0; i < 8; ++i) {
    int idx = t + 256 * i;
    int j = idx >> 4, r = idx & 15;
    int qrow = q0 + r;
    skp[j][r] = (qrow < QP) ? skip[((size_t)b * 128 + j) * QP + qrow] : 0.f;
  }
  __syncthreads();

  #pragma unroll
  for (int i = 0; i < 4; ++i) {
    int idx = t + 256 * i;
    int r = idx >> 6, jp = idx & 63;
    int qrow = q0 + r;
    float v0 = 0.f, v1 = 0.f;
    if (qrow < QP) {
      #pragma unroll
      for (int n = 0; n < 6; ++n) {
        float2 p = *(const float2*)&aw[((size_t)(b * 6 + n) * QP + qrow) * 128 + 2 * jp];
        v0 += p.x; v1 += p.y;
      }
      float iv = cc[r][jp >> 4];
      v0 *= iv; v1 *= iv;
    }
    *(uint*)((char*)xa + r * 256 + ((4 * jp) ^ ((r & 7) << 4))) = pk2(v0, v1);
  }
  __syncthreads();

  f32x4 acc1[2] = {zf, zf};
  #pragma unroll
  for (int ks = 0; ks < 4; ++ks) {
    bf16x8 a = ldfrag_swz((const char*)xa + ln15 * 256, ks * 64 + g * 16, (ln15 & 7) << 4);
    #pragma unroll
    for (int jc = 0; jc < 2; ++jc) {
      int j = (2 * w + jc) * 16 + ln15;
      bf16x8 bfr = *(const bf16x8*)&woT[j * 128 + ks * 32 + g * 8];
      acc1[jc] = __builtin_amdgcn_mfma_f32_16x16x32_bf16(a, bfr, acc1[jc], 0, 0, 0);
    }
  }
  float z[2][4];
  #pragma unroll
  for (int jc = 0; jc < 2; ++jc) {
    int j = (2 * w + jc) * 16 + ln15;
    float bj = bo[j];
    #pragma unroll
    for (int i = 0; i < 4; ++i)
      z[jc][i] = acc1[jc][i] + bj + skp[j][4 * g + i];
  }
  {
    float s_[4], q_[4];
    #pragma unroll
    for (int i = 0; i < 4; ++i) {
      s_[i] = z[0][i] + z[1][i];
      q_[i] = z[0][i] * z[0][i] + z[1][i] * z[1][i];
    }
    #pragma unroll
    for (int m = 1; m <= 8; m <<= 1) {
      #pragma unroll
      for (int i = 0; i < 4; ++i) {
        s_[i] += __shfl_xor(s_[i], m);
        q_[i] += __shfl_xor(q_[i], m);
      }
    }
    if (ln15 == 0) {
      #pragma unroll
      for (int i = 0; i < 4; ++i) red[w][4 * g + i] = make_float2(s_[i], q_[i]);
    }
  }
  __syncthreads();
  if (t < 16) {
    float S = red[0][t].x + red[1][t].x + red[2][t].x + red[3][t].x;
    float Q = red[0][t].y + red[1][t].y + red[2][t].y + red[3][t].y;
    float mu = S * (1.f / 128.f);
    float var = Q * (1.f / 128.f) - mu * mu;
    mu_s[t] = mu; rs_s[t] = rsqrtf(var + LNEPS);
  }
  __syncthreads();
  float zn[2][4];
  #pragma unroll
  for (int jc = 0; jc < 2; ++jc) {
    int j = (2 * w + jc) * 16 + ln15;
    float lw = lnpw[j], lb = lnpb[j];
    #pragma unroll
    for (int i = 0; i < 4; ++i) {
      int r = 4 * g + i;
      float v = (z[jc][i] - mu_s[r]) * rs_s[r] * lw + lb;
      zn[jc][i] = v;
      *(ushort*)((char*)znb + r * 256 + ((2 * j) ^ ((r & 7) << 4))) = f2bf(v);
    }
  }
  __syncthreads();

  f32x4 acc2[4] = {zf, zf, zf, zf};
  #pragma unroll
  for (int ks = 0; ks < 4; ++ks) {
    bf16x8 a = ldfrag_swz((const char*)znb + ln15 * 256, ks * 64 + g * 16, (ln15 & 7) << 4);
    #pragma unroll
    for (int jc2 = 0; jc2 < 4; ++jc2) {
      int j2 = (4 * w + jc2) * 16 + ln15;
      bf16x8 bfr = *(const bf16x8*)&w1T[j2 * 128 + ks * 32 + g * 8];
      acc2[jc2] = __builtin_amdgcn_mfma_f32_16x16x32_bf16(a, bfr, acc2[jc2], 0, 0, 0);
    }
  }
  #pragma unroll
  for (int jc2 = 0; jc2 < 4; ++jc2) {
    int j2 = (4 * w + jc2) * 16 + ln15;
    float bj = b1[j2];
    #pragma unroll
    for (int i = 0; i < 4; ++i) {
      float x = acc2[jc2][i] + bj;
      float ge = 0.5f * x * (1.f + erff(x * 0.70710678118654752f));
      int r = 4 * g + i;
      *(ushort*)((char*)hb + r * 512 + ((2 * j2) ^ ((r & 7) << 4))) = f2bf(ge);
    }
  }
  __syncthreads();

  f32x4 acc3[2] = {zf, zf};
  #pragma unroll
  for (int ks = 0; ks < 8; ++ks) {
    bf16x8 a = ldfrag_swz((const char*)hb + ln15 * 512, ks * 64 + g * 16, (ln15 & 7) << 4);
    #pragma unroll
    for (int jc = 0; jc < 2; ++jc) {
      int j = (2 * w + jc) * 16 + ln15;
      bf16x8 bfr = *(const bf16x8*)&w2T[j * 256 + ks * 32 + g * 8];
      acc3[jc] = __builtin_amdgcn_mfma_f32_16x16x32_bf16(a, bfr, acc3[jc], 0, 0, 0);
    }
  }
  float z2[2][4];
  #pragma unroll
  for (int jc = 0; jc < 2; ++jc) {
    int j = (2 * w + jc) * 16 + ln15;
    float bj = b2[j];
    #pragma unroll
    for (int i = 0; i < 4; ++i)
      z2[jc][i] = acc3[jc][i] + bj + zn[jc][i];
  }
  {
    float s_[4], q_[4];
    #pragma unroll
    for (int i = 0; i < 4; ++i) {
      s_[i] = z2[0][i] + z2[1][i];
      q_[i] = z2[0][i] * z2[0][i] + z2[1][i] * z2[1][i];
    }
    #pragma unroll
    for (int m = 1; m <= 8; m <<= 1) {
      #pragma unroll
      for (int i = 0; i < 4; ++i) {
        s_[i] += __shfl_xor(s_[i], m);
        q_[i] += __shfl_xor(q_[i], m);
      }
    }
    if (ln15 == 0) {
      #pragma unroll
      for (int i = 0; i < 4; ++i) red[w][4 * g + i] = make_float2(s_[i], q_[i]);
    }
  }
  __syncthreads();
  if (t < 16) {
    float S = red[0][t].x + red[1][t].x + red[2][t].x + red[3][t].x;
    float Q = red[0][t].y + red[1][t].y + red[2][t].y + red[3][t].y;
    float mu = S * (1.f / 128.f);
    float var = Q * (1.f / 128.f) - mu * mu;
    mu_s[t] = mu; rs_s[t] = rsqrtf(var + LNEPS);
  }
  __syncthreads();
  #pragma unroll
  for (int jc = 0; jc < 2; ++jc) {
    int j = (2 * w + jc) * 16 + ln15;
    float lw = lnqw[j], lb = lnqb[j];
    #pragma unroll
    for (int i = 0; i < 4; ++i) {
      int r = 4 * g + i;
      skp[j][r] = (z2[jc][i] - mu_s[r]) * rs_s[r] * lw + lb;
    }
  }
  __syncthreads();
  #pragma unroll
  for (int i = 0; i < 8; ++i) {
    int idx = t + 256 * i;
    int j = idx >> 4, r = idx & 15;
    int qrow = q0 + r;
    if (qrow < QP)
      out[((size_t)b * 128 + j) * QP + qrow] = skp[j][r];
  }
}

extern "C" void kernel_launch(void* const* d_in, const int* in_sizes, int n_in,
                              void* d_out, int out_size, void* d_ws, size_t ws_size,
                              hipStream_t stream) {
  const float* q       = (const float*)d_in[0];
  const float* k       = (const float*)d_in[1];
  const float* v       = (const float*)d_in[2];
  const float* skip    = (const float*)d_in[3];
  const float* ln_q_w  = (const float*)d_in[4];
  const float* ln_q_b  = (const float*)d_in[5];
  const float* wq      = (const float*)d_in[6];
  const float* bq      = (const float*)d_in[7];
  const float* ln_k_w  = (const float*)d_in[8];
  const float* ln_k_b  = (const float*)d_in[9];
  const float* wk      = (const float*)d_in[10];
  const float* bk      = (const float*)d_in[11];
  const float* ln_v_w  = (const float*)d_in[12];
  const float* ln_v_b  = (const float*)d_in[13];
  const float* wv      = (const float*)d_in[14];
  const float* bv      = (const float*)d_in[15];
  const float* wo      = (const float*)d_in[16];
  const float* bo      = (const float*)d_in[17];
  const float* ln_pre_w  = (const float*)d_in[18];
  const float* ln_pre_b  = (const float*)d_in[19];
  const float* w1      = (const float*)d_in[20];
  const float* b1      = (const float*)d_in[21];
  const float* w2      = (const float*)d_in[22];
  const float* b2      = (const float*)d_in[23];
  const float* ln_post_w = (const float*)d_in[24];
  const float* ln_post_b = (const float*)d_in[25];

  float* out = (float*)d_out;
  ushort* qhp  = (ushort*)d_ws;            // 3,840,000 bf16
  ushort* kimg = qhp + 3840000;            // 2,064,384 bf16
  ushort* vimg = kimg + 2064384;           // 2,064,384 bf16
  ushort* wtq  = vimg + 2064384;           // 16,384 bf16
  ushort* wtk  = wtq + 16384;
  ushort* wtv  = wtk + 16384;
  ushort* woT  = wtv + 16384;              // 16,384 bf16
  ushort* w1T  = woT + 16384;              // 32,768 bf16
  ushort* w2T  = w1T + 32768;              // 32,768 bf16
  float*  aw   = (float*)(w2T + 32768);    // [bn][q][128] = 3,840,000 f32
  float*  ml   = aw + 3840000;             // [bn][q][h] = 120,000 f32

  wprep_kernel<<<dim3(32, 6), 256, 0, stream>>>(wq, wk, wv, wo, w1, w2,
      wtq, wtk, wtv, woT, w1T, w2T);
  proj_kernel<<<dim3(40, 12, 3), 256, 0, stream>>>(q, k, v,
      ln_q_w, ln_q_b, ln_k_w, ln_k_b, ln_v_w, ln_v_b,
      wtq, wtk, wtv, bq, bk, bv, qhp, kimg, vimg);
  attn_kernel<<<dim3(40, 4, 12), 256, 0, stream>>>(qhp, kimg, vimg, aw, ml);
  epilogue_kernel<<<dim3(157, 2), 256, 0, stream>>>(aw, ml, skip, woT, bo,
      ln_pre_w, ln_pre_b, w1T, b1, w2T, b2, ln_post_w, ln_post_b, out);
}